// Round 9
// baseline (311.109 us; speedup 1.0000x reference)
//
#include <hip/hip_runtime.h>
#include <math.h>

#define NS 20000
#define TT 6890
#define TPAD 6912
#define FE 128
#define EDG 640000
#define DEG 32

#define SPC 54            // 32-col strips per T-quarter chunk
#define CHCOLS 1728       // cols per chunk (4 chunks = 6912)
#define RECSH 4096        // shorts per strip record (8192 B, fragments only)

typedef __attribute__((ext_vector_type(8))) short short8;     // 8 bf16
typedef __attribute__((ext_vector_type(4))) float floatx4;    // MFMA C/D
typedef unsigned int uint;

__device__ __forceinline__ unsigned short f2bf(float f) {
  unsigned int u = __float_as_uint(f);
  return (unsigned short)((u + 0x7fffu + ((u >> 16) & 1u)) >> 16);  // RNE
}

__device__ __forceinline__ void dma16(const void* g, void* l) {
  __builtin_amdgcn_global_load_lds(
      (const __attribute__((address_space(1))) unsigned int*)g,
      (__attribute__((address_space(3))) unsigned int*)l, 16, 0, 0);
}

// ---------------- K0: swizzled strip records + tn + tn256 ----------------
// Record s: 32 cols x 256 B. 16B chunk jj of col c stored at slot jj^(c&7):
// DMA write (lane-ordered) and MFMA ds_read both become <=2-way conflicts.
__global__ void tn_cast_kernel(const float* __restrict__ tf, float* __restrict__ tn,
                               float* __restrict__ tn256,
                               unsigned short* __restrict__ tfbx) {
  int gid = blockIdx.x * blockDim.x + threadIdx.x;
  int w = gid >> 6;
  int lane = gid & 63;
  if (w >= TPAD) return;
  int strip = w >> 5, c = w & 31;
  unsigned short* base = tfbx + (size_t)strip * RECSH;
  int jj = lane >> 2;                       // 16B chunk 0..15
  int soff = c * 128 + ((jj ^ (c & 7)) << 3) + (lane & 3) * 2;
  if (w < TT) {
    const float* p = tf + (size_t)w * FE;
    float a = p[lane];
    float b = p[lane + 64];
    float s = a * a + b * b;
#pragma unroll
    for (int off = 32; off > 0; off >>= 1) s += __shfl_xor(s, off);
    if (lane == 0) { tn[w] = s; tn256[w] = s + 256.0f; }
    ushort2 o;
    o.x = f2bf(p[2 * lane]);
    o.y = f2bf(p[2 * lane + 1]);
    *reinterpret_cast<ushort2*>(base + soff) = o;
  } else {
    if (lane == 0) { tn[w] = 1e30f; tn256[w] = 3e38f; }  // pads never win
    ushort2 z; z.x = 0; z.y = 0;
    *reinterpret_cast<ushort2*>(base + soff) = z;
  }
}

// ---------------- K1: async-DMA double-buffered LDS, barrier-free K-loop ----------------
// Block = 32 rows x 4 waves; wave wv owns T-chunk wv (54 strips). Strip s+1 is
// DMA'd (global_load_lds, no VGPR cost) into the idle wave-private 8KB buffer
// while strip s is consumed from the other; one explicit vmcnt(0) per strip is
// the only wait. Per-(lane,h) top-6 packed keys: key = (bits(tn+256-2dp) &
// ~0x1FFF) | col (metric > 0 so uint order == float order), 12-op insert.
union SmemU {
  unsigned short tiles[4][2][RECSH];   // 4 waves x 2 bufs x 8 KB = 64 KB
  struct {
    uint  pk[32][25];
    float pv[32][25];
  } e;
};

__global__ __launch_bounds__(256, 2) void topk_kernel(
    const float* __restrict__ sf, const float* __restrict__ tf,
    const unsigned short* __restrict__ tfbx, const float* __restrict__ tn,
    const float* __restrict__ tn256, const float* __restrict__ tp,
    float* __restrict__ pred) {
  __shared__ SmemU u;
  const int tid = threadIdx.x;
  const int lane = tid & 63;
  const int wv = tid >> 6;             // chunk id 0..3
  const int q = lane >> 4;
  const int m = lane & 15;
  const int row0 = blockIdx.x * 32;    // exact: 625*32 = 20000

  // resident B-operand fragments: rows row0 + h*16 + m
  short8 bf[2][4];
#pragma unroll
  for (int h = 0; h < 2; ++h) {
    const float* src = sf + (size_t)(row0 + h * 16 + m) * FE;
#pragma unroll
    for (int ks = 0; ks < 4; ++ks) {
      float4 f0 = *reinterpret_cast<const float4*>(src + ks * 32 + q * 8);
      float4 f1 = *reinterpret_cast<const float4*>(src + ks * 32 + q * 8 + 4);
      union { unsigned short us[8]; short8 s8; } t;
      t.us[0] = f2bf(f0.x); t.us[1] = f2bf(f0.y);
      t.us[2] = f2bf(f0.z); t.us[3] = f2bf(f0.w);
      t.us[4] = f2bf(f1.x); t.us[5] = f2bf(f1.y);
      t.us[6] = f2bf(f1.z); t.us[7] = f2bf(f1.w);
      bf[h][ks] = t.s8;
    }
  }

  uint kq[2][6];
#pragma unroll
  for (int h = 0; h < 2; ++h)
#pragma unroll
    for (int k = 0; k < 6; ++k) kq[h][k] = 0xFFFFFFFFu;

  // swizzled ds_read offsets (shorts): (a*16+m)*128 + ((ks*4+q)^(m&7))*8
  int rd[8];
#pragma unroll
  for (int a = 0; a < 2; ++a)
#pragma unroll
    for (int ks = 0; ks < 4; ++ks)
      rd[a * 4 + ks] = (a * 16 + m) * 128 + (((ks * 4 + q) ^ (m & 7)) << 3);

  const int sbase = wv * SPC;
  const int cbase = wv * CHCOLS;
  const int s0 = (blockIdx.x * 7) % SPC;   // stagger across blocks

  float4 tnb[2][2];

  // prologue: DMA strip s0 into buf 0 + its tn loads
  {
    const char* gs = (const char*)tfbx + (size_t)(sbase + s0) * 8192 + lane * 16;
    char* ls = (char*)&u.tiles[wv][0][0];
#pragma unroll
    for (int i = 0; i < 8; ++i) dma16(gs + i * 1024, ls + i * 1024);
    const float* tnp = tn256 + cbase + s0 * 32;
    tnb[0][0] = *reinterpret_cast<const float4*>(tnp + q * 4);
    tnb[0][1] = *reinterpret_cast<const float4*>(tnp + 16 + q * 4);
  }

  for (int ss = 0; ss < SPC; ++ss) {
    const int cur = ss & 1;
    int s = s0 + ss; if (s >= SPC) s -= SPC;
    const int col0 = cbase + s * 32;

    __builtin_amdgcn_s_waitcnt(0x0F70);          // vmcnt(0): DMA(s)+tn(s) done
    __builtin_amdgcn_sched_barrier(0);

    const unsigned short* tb = &u.tiles[wv][cur][0];
    short8 fr[8];
#pragma unroll
    for (int j = 0; j < 8; ++j)
      fr[j] = *reinterpret_cast<const short8*>(tb + rd[j]);
    __builtin_amdgcn_sched_barrier(0);

    if (ss + 1 < SPC) {                          // DMA next strip (idle buffer)
      int s1 = s + 1; if (s1 >= SPC) s1 -= SPC;
      const char* gs = (const char*)tfbx + (size_t)(sbase + s1) * 8192 + lane * 16;
      char* ls = (char*)&u.tiles[wv][cur ^ 1][0];
#pragma unroll
      for (int i = 0; i < 8; ++i) dma16(gs + i * 1024, ls + i * 1024);
      const float* tnp = tn256 + cbase + s1 * 32;
      tnb[cur ^ 1][0] = *reinterpret_cast<const float4*>(tnp + q * 4);
      tnb[cur ^ 1][1] = *reinterpret_cast<const float4*>(tnp + 16 + q * 4);
    }
    __builtin_amdgcn_sched_barrier(0);

#pragma unroll
    for (int a = 0; a < 2; ++a) {
      floatx4 acc0 = (floatx4){0.f, 0.f, 0.f, 0.f};
      floatx4 acc1 = (floatx4){0.f, 0.f, 0.f, 0.f};
#pragma unroll
      for (int ks = 0; ks < 4; ++ks) {
        acc0 = __builtin_amdgcn_mfma_f32_16x16x32_bf16(fr[a * 4 + ks], bf[0][ks], acc0, 0, 0, 0);
        acc1 = __builtin_amdgcn_mfma_f32_16x16x32_bf16(fr[a * 4 + ks], bf[1][ks], acc1, 0, 0, 0);
      }
      float tv[4] = {tnb[cur][a].x, tnb[cur][a].y, tnb[cur][a].z, tnb[cur][a].w};
      const uint cb = (uint)(col0 + a * 16 + q * 4);
#pragma unroll
      for (int r = 0; r < 4; ++r) {
        float met0 = fmaf(-2.f, acc0[r], tv[r]);             // > 0 always
        float met1 = fmaf(-2.f, acc1[r], tv[r]);
        uint t0 = (__float_as_uint(met0) & 0xFFFFE000u) | (cb + (uint)r);
        uint t1 = (__float_as_uint(met1) & 0xFFFFE000u) | (cb + (uint)r);
#pragma unroll
        for (int k = 0; k < 6; ++k) {                         // branchless inserts
          uint lo0 = min(kq[0][k], t0), hi0 = max(kq[0][k], t0);
          kq[0][k] = lo0; t0 = hi0;
          uint lo1 = min(kq[1][k], t1), hi1 = max(kq[1][k], t1);
          kq[1][k] = lo1; t1 = hi1;
        }
      }
    }
  }

  // butterfly shfl merge across the 4 q-lanes -> top-6 of this wave's chunk
#pragma unroll
  for (int h = 0; h < 2; ++h) {
#pragma unroll
    for (int st = 16; st <= 32; st <<= 1) {
      uint inc[6];
#pragma unroll
      for (int k = 0; k < 6; ++k) inc[k] = __shfl_xor(kq[h][k], st);
#pragma unroll
      for (int k = 0; k < 6; ++k) {
        uint t = inc[k];
#pragma unroll
        for (int j = 0; j < 6; ++j) {
          uint lo = min(kq[h][j], t);
          uint hi = max(kq[h][j], t);
          kq[h][j] = lo;
          t = hi;
        }
      }
    }
  }
  __syncthreads();   // all waves done with tiles; safe to overlay epilogue
  if (q == 0) {
#pragma unroll
    for (int h = 0; h < 2; ++h)
#pragma unroll
      for (int k = 0; k < 6; ++k) u.e.pk[h * 16 + m][wv * 6 + k] = kq[h][k];
  }
  __syncthreads();

  // fp32 rescore (exact round-1 arithmetic): 32 rows x 24 cands = 768 dots
#pragma unroll
  for (int j = 0; j < 3; ++j) {
    int idx = j * 256 + tid;            // < 768
    int r = idx / 24;
    int c = idx - r * 24;
    int col = (int)(u.e.pk[r][c] & 0x1FFFu);
    const float* srow = sf + (size_t)(row0 + r) * FE;
    const float* trow = tf + (size_t)col * FE;
    float accv = 0.f;
#pragma unroll 8
    for (int kk = 0; kk < FE; kk += 4) {
      float4 av = *reinterpret_cast<const float4*>(srow + kk);
      float4 bv = *reinterpret_cast<const float4*>(trow + kk);
      accv += av.x * bv.x + av.y * bv.y + av.z * bv.z + av.w * bv.w;
    }
    u.e.pv[r][c] = tn[col] - 2.f * accv;
  }
  __syncthreads();

  // exact top-6 of 24, softmax, gather
  if (tid < 32) {
    float sd[6]; int sp6[6];
#pragma unroll
    for (int k = 0; k < 6; ++k) { sd[k] = 1e30f; sp6[k] = 0; }
    for (int j = 0; j < 24; ++j) {
      float v = u.e.pv[tid][j];
      if (v < sd[5]) {
        sd[5] = v; sp6[5] = j;
#pragma unroll
        for (int k = 4; k >= 0; --k) {
          if (sd[k + 1] < sd[k]) {
            float tvv = sd[k]; sd[k] = sd[k + 1]; sd[k + 1] = tvv;
            int tii = sp6[k]; sp6[k] = sp6[k + 1]; sp6[k + 1] = tii;
          }
        }
      }
    }
    float wgt[6]; float wsum = 0.f;
#pragma unroll
    for (int k = 0; k < 6; ++k) { wgt[k] = __expf(sd[0] - sd[k]); wsum += wgt[k]; }
    float inv = 1.f / wsum;
    float px = 0.f, py = 0.f, pz = 0.f;
#pragma unroll
    for (int k = 0; k < 6; ++k) {
      float sc = wgt[k] * inv;
      const float* qq = tp + (size_t)(u.e.pk[tid][sp6[k]] & 0x1FFFu) * 3;
      px += sc * qq[0]; py += sc * qq[1]; pz += sc * qq[2];
    }
    int g = row0 + tid;
    pred[g * 3 + 0] = px;
    pred[g * 3 + 1] = py;
    pred[g * 3 + 2] = pz;
  }
}

// ---------------- K2: per-node Procrustes (3x3 SVD, fp64 Jacobi) ----------------
__global__ __launch_bounds__(64) void proc_kernel(
    const int* __restrict__ colp, const float* __restrict__ pos,
    const float* __restrict__ pred, float* __restrict__ Rout,
    float* __restrict__ tout, float* __restrict__ qnorm) {
  int i = blockIdx.x * blockDim.x + threadIdx.x;
  if (i >= NS) return;
  int4 cia[8];
#pragma unroll
  for (int t = 0; t < 8; ++t)
    cia[t] = reinterpret_cast<const int4*>(colp + (size_t)i * DEG)[t];
  const int* cidx = reinterpret_cast<const int*>(cia);

  double sp[3] = {0, 0, 0}, sq[3] = {0, 0, 0};
  double spq[3][3] = {{0, 0, 0}, {0, 0, 0}, {0, 0, 0}};
#pragma unroll
  for (int e = 0; e < DEG; ++e) {
    int c = cidx[e];
    double p0 = pos[c * 3], p1 = pos[c * 3 + 1], p2 = pos[c * 3 + 2];
    double q0 = pred[c * 3], q1 = pred[c * 3 + 1], q2 = pred[c * 3 + 2];
    sp[0] += p0; sp[1] += p1; sp[2] += p2;
    sq[0] += q0; sq[1] += q1; sq[2] += q2;
    spq[0][0] += p0 * q0; spq[0][1] += p0 * q1; spq[0][2] += p0 * q2;
    spq[1][0] += p1 * q0; spq[1][1] += p1 * q1; spq[1][2] += p1 * q2;
    spq[2][0] += p2 * q0; spq[2][1] += p2 * q1; spq[2][2] += p2 * q2;
  }
  const double inv = 1.0 / 32.0;
  double A[3][3], sc[3], tcn[3];
  for (int a = 0; a < 3; ++a) {
    sc[a] = sp[a] * inv;
    tcn[a] = sq[a] * inv;
  }
  for (int a = 0; a < 3; ++a)
    for (int b = 0; b < 3; ++b) A[a][b] = spq[a][b] - sp[a] * sq[b] * inv;

  double S[3][3];
  for (int a = 0; a < 3; ++a)
    for (int b = 0; b < 3; ++b)
      S[a][b] = A[0][a] * A[0][b] + A[1][a] * A[1][b] + A[2][a] * A[2][b];
  double V[3][3] = {{1, 0, 0}, {0, 1, 0}, {0, 0, 1}};
  const int JP[3] = {0, 0, 1}, JQ[3] = {1, 2, 2};
  for (int sweep = 0; sweep < 6; ++sweep) {
    for (int r = 0; r < 3; ++r) {
      int p = JP[r], q = JQ[r];
      double apq = S[p][q];
      if (fabs(apq) < 1e-300) continue;
      double theta = (S[q][q] - S[p][p]) / (2.0 * apq);
      double t = copysign(1.0 / (fabs(theta) + sqrt(theta * theta + 1.0)), theta);
      double c = 1.0 / sqrt(t * t + 1.0);
      double s = t * c;
      double spp = S[p][p], sqq = S[q][q];
      S[p][p] = spp - t * apq;
      S[q][q] = sqq + t * apq;
      S[p][q] = 0.0; S[q][p] = 0.0;
      int k = 3 - p - q;
      double skp = S[k][p], skq = S[k][q];
      S[k][p] = S[p][k] = c * skp - s * skq;
      S[k][q] = S[q][k] = s * skp + c * skq;
      for (int mth = 0; mth < 3; ++mth) {
        double vp = V[mth][p], vq = V[mth][q];
        V[mth][p] = c * vp - s * vq;
        V[mth][q] = s * vp + c * vq;
      }
    }
  }
  double lam[3] = {S[0][0], S[1][1], S[2][2]};
  int i0 = 0, i1 = 1, i2 = 2, tmp;
  if (lam[i0] < lam[i1]) { tmp = i0; i0 = i1; i1 = tmp; }
  if (lam[i0] < lam[i2]) { tmp = i0; i0 = i2; i2 = tmp; }
  if (lam[i1] < lam[i2]) { tmp = i1; i1 = i2; i2 = tmp; }
  double v0[3] = {V[0][i0], V[1][i0], V[2][i0]};
  double v1[3] = {V[0][i1], V[1][i1], V[2][i1]};
  double v2[3] = {V[0][i2], V[1][i2], V[2][i2]};

  double Av0[3], Av1[3], Av2[3];
  for (int a = 0; a < 3; ++a) {
    Av0[a] = A[a][0] * v0[0] + A[a][1] * v0[1] + A[a][2] * v0[2];
    Av1[a] = A[a][0] * v1[0] + A[a][1] * v1[1] + A[a][2] * v1[2];
    Av2[a] = A[a][0] * v2[0] + A[a][1] * v2[1] + A[a][2] * v2[2];
  }
  double n0 = fmax(sqrt(Av0[0]*Av0[0] + Av0[1]*Av0[1] + Av0[2]*Av0[2]), 1e-300);
  double u0[3] = {Av0[0] / n0, Av0[1] / n0, Av0[2] / n0};
  double proj = u0[0]*Av1[0] + u0[1]*Av1[1] + u0[2]*Av1[2];
  double u1[3] = {Av1[0] - proj * u0[0], Av1[1] - proj * u0[1], Av1[2] - proj * u0[2]};
  double n1 = fmax(sqrt(u1[0]*u1[0] + u1[1]*u1[1] + u1[2]*u1[2]), 1e-300);
  u1[0] /= n1; u1[1] /= n1; u1[2] /= n1;
  double w[3] = {u0[1]*u1[2] - u0[2]*u1[1],
                 u0[2]*u1[0] - u0[0]*u1[2],
                 u0[0]*u1[1] - u0[1]*u1[0]};
  double dotw = Av2[0]*w[0] + Av2[1]*w[1] + Av2[2]*w[2];
  double sgn = (dotw < 0.0) ? -1.0 : 1.0;
  double detA = A[0][0]*(A[1][1]*A[2][2] - A[1][2]*A[2][1])
              - A[0][1]*(A[1][0]*A[2][2] - A[1][2]*A[2][0])
              + A[0][2]*(A[1][0]*A[2][1] - A[1][1]*A[2][0]);
  double d3 = ((detA < 0.0) ? -1.0 : 1.0) * sgn;

  double R[3][3];
  for (int a = 0; a < 3; ++a)
    for (int b = 0; b < 3; ++b)
      R[a][b] = u0[a]*v0[b] + u1[a]*v1[b] + d3 * w[a]*v2[b];

  for (int a = 0; a < 3; ++a)
    for (int b = 0; b < 3; ++b) Rout[i * 9 + a * 3 + b] = (float)R[a][b];
  double tr_[3];
  for (int a = 0; a < 3; ++a) {
    tr_[a] = tcn[a] - (R[a][0]*sc[0] + R[a][1]*sc[1] + R[a][2]*sc[2]);
    tout[i * 3 + a] = (float)tr_[a];
  }
  double pxi = pos[i * 3], pyi = pos[i * 3 + 1], pzi = pos[i * 3 + 2];
  double r0 = R[0][0]*pxi + R[0][1]*pyi + R[0][2]*pzi + tr_[0] - pred[i * 3];
  double r1 = R[1][0]*pxi + R[1][1]*pyi + R[1][2]*pzi + tr_[1] - pred[i * 3 + 1];
  double r2 = R[2][0]*pxi + R[2][1]*pyi + R[2][2]*pzi + tr_[2] - pred[i * 3 + 2];
  qnorm[i] = (float)(r0 * r0 + r1 * r1 + r2 * r2);
}

// ---------------- K3: per-node residual mean over neighbors ----------------
__global__ __launch_bounds__(64) void dst_kernel(
    const int* __restrict__ colp, const float* __restrict__ qn,
    float* __restrict__ dout) {
  int i = blockIdx.x * blockDim.x + threadIdx.x;
  if (i >= NS) return;
  int4 cia[8];
#pragma unroll
  for (int t = 0; t < 8; ++t)
    cia[t] = reinterpret_cast<const int4*>(colp + (size_t)i * DEG)[t];
  const int* cidx = reinterpret_cast<const int*>(cia);
  float s = 0.f;
#pragma unroll
  for (int e = 0; e < DEG; ++e) s += qn[cidx[e]];
  dout[i] = s * (1.0f / 32.0f);
}

extern "C" void kernel_launch(void* const* d_in, const int* in_sizes, int n_in,
                              void* d_out, int out_size, void* d_ws, size_t ws_size,
                              hipStream_t stream) {
  const float* sf  = (const float*)d_in[0];   // [N,128]
  const float* tf  = (const float*)d_in[1];   // [T,128]
  const float* tp  = (const float*)d_in[2];   // [T,3]
  const float* pos = (const float*)d_in[3];   // [N,3]
  const int*   ei  = (const int*)d_in[4];     // [2,E]
  float* out = (float*)d_out;                 // [N*9 | N*3 | N]
  char* ws = (char*)d_ws;
  // ws layout (~2.07 MB; qn aliases tfbx which is dead after topk):
  float*          tn    = (float*)(ws);                   // 27,648 B
  float*          tn256 = (float*)(ws + 28672);           // 27,648 B
  float*          pred  = (float*)(ws + 57344);           // 240,000 B
  unsigned short* tfbx  = (unsigned short*)(ws + 303104); // 216*8192 = 1,769,472 B
  float*          qn    = (float*)(ws + 303104);          // alias (post-topk)
  const int* colp = ei + EDG;

  tn_cast_kernel<<<(TPAD * 64) / 256, 256, 0, stream>>>(tf, tn, tn256, tfbx);
  topk_kernel<<<NS / 32, 256, 0, stream>>>(sf, tf, tfbx, tn, tn256, tp, pred);
  proc_kernel<<<(NS + 63) / 64, 64, 0, stream>>>(colp, pos, pred, out,
                                                 out + NS * 9, qn);
  dst_kernel<<<(NS + 63) / 64, 64, 0, stream>>>(colp, qn, out + NS * 12);
}

// Round 10
// 255.654 us; speedup vs baseline: 1.2169x; 1.2169x over previous
//
#include <hip/hip_runtime.h>
#include <math.h>

#define NS 20000
#define TT 6890
#define TPAD 6912
#define FE 128
#define EDG 640000
#define DEG 32

#define RPB 160           // rows per block (10 rowsets) -> 125 row-blocks exact
#define NCB 4             // col-blocks
#define CBW 1728          // cols per col-block
#define NSTR 27           // 64-col strips per col-block

typedef __attribute__((ext_vector_type(8))) short short8;     // 8 bf16
typedef __attribute__((ext_vector_type(4))) float floatx4;    // MFMA C/D
typedef unsigned int uint;

__device__ __forceinline__ unsigned short f2bf(float f) {
  unsigned int u = __float_as_uint(f);
  return (unsigned short)((u + 0x7fffu + ((u >> 16) & 1u)) >> 16);  // RNE
}

// ---------------- K0: col-major swizzled bf16 records + tn + tn256 ----------------
// Col w: 256 B at tfbx + w*128 shorts; 16B chunk jj stored at slot jj^(w&7).
__global__ void tn_cast_kernel(const float* __restrict__ tf, float* __restrict__ tn,
                               float* __restrict__ tn256,
                               unsigned short* __restrict__ tfbx) {
  int gid = blockIdx.x * blockDim.x + threadIdx.x;
  int w = gid >> 6;
  int lane = gid & 63;
  if (w >= TPAD) return;
  unsigned short* base = tfbx + (size_t)w * 128;
  int jj = lane >> 2;
  int soff = ((jj ^ (w & 7)) << 3) + (lane & 3) * 2;
  if (w < TT) {
    const float* p = tf + (size_t)w * FE;
    float a = p[lane];
    float b = p[lane + 64];
    float s = a * a + b * b;
#pragma unroll
    for (int off = 32; off > 0; off >>= 1) s += __shfl_xor(s, off);
    if (lane == 0) { tn[w] = s; tn256[w] = s + 256.0f; }
    ushort2 o;
    o.x = f2bf(p[2 * lane]);
    o.y = f2bf(p[2 * lane + 1]);
    *reinterpret_cast<ushort2*>(base + soff) = o;
  } else {
    if (lane == 0) { tn[w] = 1e30f; tn256[w] = 3e38f; }  // pads never win
    ushort2 z; z.x = 0; z.y = 0;
    *reinterpret_cast<ushort2*>(base + soff) = z;
  }
}

// ---------------- K1: 160-row LDS-stationary GEMM + per-substream top-6 ----------------
// Block = 160 source rows (LDS once) x 1728 target cols (27 strips x 64).
// Wave wv owns cols wv*16..+15 of each strip. MFMA: A = target cols (D-row =
// tcol), B = source rowset (D-col = srow m). Per-(lane, rowset) top-6 packed
// keys: key = (bits(tn+256-2dp) & ~0x1FFF) | col (metric > 0 => uint order ==
// float order). q-shfl merge -> 24/row -> in-block top-12 per cb -> pkall.
union SmemK1 {
  struct {
    unsigned short Bs[RPB * 128];   // 40960 B stationary source rows
    unsigned short As[64 * 128];    // 16384 B strip tile
  } m;
  struct {
    uint pk[RPB][24];               // 15360 B epilogue overlay
  } e;
};

__global__ __launch_bounds__(256, 2) void topk_kernel(
    const float* __restrict__ sf, const unsigned short* __restrict__ tfbx,
    const float* __restrict__ tn256, uint* __restrict__ pkall) {
  __shared__ SmemK1 u;
  const int tid = threadIdx.x;
  const int lane = tid & 63;
  const int wv = tid >> 6;
  const int q = lane >> 4;
  const int m = lane & 15;
  const int rb = (int)blockIdx.x >> 2;
  const int cb = (int)blockIdx.x & 3;
  const int row0 = rb * RPB;          // exact: 125*160 = 20000
  const int cbase = cb * CBW;

  // one-time stage: source rows -> Bs (bf16, swizzled)
  if (tid < RPB) {
    const float* src = sf + (size_t)(row0 + tid) * FE;
    unsigned short* dst = u.m.Bs + tid * 128;
    const int sw = tid & 7;
#pragma unroll
    for (int jj = 0; jj < 16; ++jj) {
      float4 f0 = *reinterpret_cast<const float4*>(src + jj * 8);
      float4 f1 = *reinterpret_cast<const float4*>(src + jj * 8 + 4);
      union { unsigned short us[8]; uint4 v; } t;
      t.us[0] = f2bf(f0.x); t.us[1] = f2bf(f0.y);
      t.us[2] = f2bf(f0.z); t.us[3] = f2bf(f0.w);
      t.us[4] = f2bf(f1.x); t.us[5] = f2bf(f1.y);
      t.us[6] = f2bf(f1.z); t.us[7] = f2bf(f1.w);
      *reinterpret_cast<uint4*>(dst + ((jj ^ sw) << 3)) = t.v;
    }
  }

  uint kq[10][6];
#pragma unroll
  for (int h = 0; h < 10; ++h)
#pragma unroll
    for (int k = 0; k < 6; ++k) kq[h][k] = 0xFFFFFFFFu;

  int rdA[4], rdB[4];
#pragma unroll
  for (int ks = 0; ks < 4; ++ks) {
    rdA[ks] = (wv * 16 + m) * 128 + (((ks * 4 + q) ^ (m & 7)) << 3);
    rdB[ks] = m * 128 + (((ks * 4 + q) ^ (m & 7)) << 3);
  }

  __syncthreads();

  for (int s = 0; s < NSTR; ++s) {
    // stage A tile: straight 16 KB copy (swizzle preserved verbatim)
    {
      const uint4* g = reinterpret_cast<const uint4*>(
          reinterpret_cast<const char*>(tfbx) + (size_t)(cbase + s * 64) * 256 +
          tid * 64);
      uint4 a0 = g[0], a1 = g[1], a2 = g[2], a3 = g[3];
      uint4* d = reinterpret_cast<uint4*>(
          reinterpret_cast<char*>(u.m.As) + tid * 64);
      d[0] = a0; d[1] = a1; d[2] = a2; d[3] = a3;
    }
    float4 t4 = *reinterpret_cast<const float4*>(tn256 + cbase + s * 64 + wv * 16 + q * 4);
    __syncthreads();

    short8 af0 = *reinterpret_cast<const short8*>(u.m.As + rdA[0]);
    short8 af1 = *reinterpret_cast<const short8*>(u.m.As + rdA[1]);
    short8 af2 = *reinterpret_cast<const short8*>(u.m.As + rdA[2]);
    short8 af3 = *reinterpret_cast<const short8*>(u.m.As + rdA[3]);
    const uint cbk = (uint)(cbase + s * 64 + wv * 16 + q * 4);
    float tvv[4] = {t4.x, t4.y, t4.z, t4.w};

#pragma unroll
    for (int h = 0; h < 10; ++h) {
      const unsigned short* bb = u.m.Bs + h * 2048;
      short8 b0 = *reinterpret_cast<const short8*>(bb + rdB[0]);
      short8 b1 = *reinterpret_cast<const short8*>(bb + rdB[1]);
      short8 b2 = *reinterpret_cast<const short8*>(bb + rdB[2]);
      short8 b3 = *reinterpret_cast<const short8*>(bb + rdB[3]);
      floatx4 acc = (floatx4){0.f, 0.f, 0.f, 0.f};
      acc = __builtin_amdgcn_mfma_f32_16x16x32_bf16(af0, b0, acc, 0, 0, 0);
      acc = __builtin_amdgcn_mfma_f32_16x16x32_bf16(af1, b1, acc, 0, 0, 0);
      acc = __builtin_amdgcn_mfma_f32_16x16x32_bf16(af2, b2, acc, 0, 0, 0);
      acc = __builtin_amdgcn_mfma_f32_16x16x32_bf16(af3, b3, acc, 0, 0, 0);
#pragma unroll
      for (int r = 0; r < 4; ++r) {
        float met = fmaf(-2.f, acc[r], tvv[r]);              // > 0 always
        uint t = (__float_as_uint(met) & 0xFFFFE000u) | (cbk + (uint)r);
#pragma unroll
        for (int k = 0; k < 6; ++k) {                         // branchless insert
          uint lo = min(kq[h][k], t);
          uint hi = max(kq[h][k], t);
          kq[h][k] = lo;
          t = hi;
        }
      }
    }
    __syncthreads();
  }

  // merge across the 4 q-lanes via shfl butterfly (exact top-6 of 24)
#pragma unroll
  for (int h = 0; h < 10; ++h) {
#pragma unroll
    for (int st = 16; st <= 32; st <<= 1) {
      uint inc[6];
#pragma unroll
      for (int k = 0; k < 6; ++k) inc[k] = __shfl_xor(kq[h][k], st);
#pragma unroll
      for (int k = 0; k < 6; ++k) {
        uint t = inc[k];
#pragma unroll
        for (int j = 0; j < 6; ++j) {
          uint lo = min(kq[h][j], t);
          uint hi = max(kq[h][j], t);
          kq[h][j] = lo;
          t = hi;
        }
      }
    }
  }
  __syncthreads();   // tiles dead; overlay epilogue
  if (q == 0) {
#pragma unroll
    for (int h = 0; h < 10; ++h)
#pragma unroll
      for (int k = 0; k < 6; ++k) u.e.pk[h * 16 + m][wv * 6 + k] = kq[h][k];
  }
  __syncthreads();

  // per row: exact top-12 of the 24 (sound: row's top-6 within this cb is
  // contained in top-12 of the substream union) -> pkall[row][cb*12..]
  if (tid < RPB) {
    uint md[12];
#pragma unroll
    for (int k = 0; k < 12; ++k) md[k] = 0xFFFFFFFFu;
    for (int j = 0; j < 24; ++j) {
      uint t = u.e.pk[tid][j];
#pragma unroll
      for (int k = 0; k < 12; ++k) {
        uint lo = min(md[k], t);
        uint hi = max(md[k], t);
        md[k] = lo;
        t = hi;
      }
    }
    uint* dst = pkall + (size_t)(row0 + tid) * 48 + cb * 12;
#pragma unroll
    for (int k = 0; k < 12; ++k) dst[k] = md[k];
  }
}

// ---------------- K1b: merge 48 candidates/row, fp32 rescore, top-6, pred ----------------
__global__ __launch_bounds__(256) void merge_kernel(
    const float* __restrict__ sf, const float* __restrict__ tf,
    const float* __restrict__ tn, const uint* __restrict__ pkall,
    const float* __restrict__ tp, float* __restrict__ pred) {
  __shared__ float sv[4][24];
  __shared__ int   sc[4][24];
  const int lane = threadIdx.x & 63;
  const int wv = threadIdx.x >> 6;
  const int row = (int)blockIdx.x * 4 + wv;   // exact: 5000*4 = 20000
  uint k0 = 0xFFFFFFFFu;
  if (lane < 48) k0 = pkall[(size_t)row * 48 + lane];
  int r0 = 0;
  for (int j = 0; j < 48; ++j) {
    uint a = __shfl(k0, j);
    r0 += (a < k0) ? 1 : 0;                   // keys unique (distinct col bits)
  }
  if (lane < 48 && r0 < 24) {                 // bf16-top-24 of 48, unique slots
    int col = (int)(k0 & 0x1FFFu);
    const float* srow = sf + (size_t)row * FE;
    const float* trow = tf + (size_t)col * FE;
    float accv = 0.f;
#pragma unroll 8
    for (int kk = 0; kk < FE; kk += 4) {      // exact round-1 arithmetic
      float4 av = *reinterpret_cast<const float4*>(srow + kk);
      float4 bv = *reinterpret_cast<const float4*>(trow + kk);
      accv += av.x * bv.x + av.y * bv.y + av.z * bv.z + av.w * bv.w;
    }
    sv[wv][r0] = tn[col] - 2.f * accv;
    sc[wv][r0] = col;
  }
  __syncthreads();
  if (lane == 0) {
    float sd[6]; int sp6[6];
#pragma unroll
    for (int k = 0; k < 6; ++k) { sd[k] = 1e30f; sp6[k] = 0; }
    for (int j = 0; j < 24; ++j) {
      float v = sv[wv][j];
      if (v < sd[5]) {
        sd[5] = v; sp6[5] = j;
#pragma unroll
        for (int k = 4; k >= 0; --k) {
          if (sd[k + 1] < sd[k]) {
            float tvv = sd[k]; sd[k] = sd[k + 1]; sd[k + 1] = tvv;
            int tii = sp6[k]; sp6[k] = sp6[k + 1]; sp6[k + 1] = tii;
          }
        }
      }
    }
    float wgt[6]; float wsum = 0.f;
#pragma unroll
    for (int k = 0; k < 6; ++k) { wgt[k] = __expf(sd[0] - sd[k]); wsum += wgt[k]; }
    float inv = 1.f / wsum;
    float px = 0.f, py = 0.f, pz = 0.f;
#pragma unroll
    for (int k = 0; k < 6; ++k) {
      float scv = wgt[k] * inv;
      const float* qq = tp + (size_t)sc[wv][sp6[k]] * 3;
      px += scv * qq[0]; py += scv * qq[1]; pz += scv * qq[2];
    }
    pred[row * 3 + 0] = px;
    pred[row * 3 + 1] = py;
    pred[row * 3 + 2] = pz;
  }
}

// ---------------- K2: per-node Procrustes (3x3 SVD, fp64 Jacobi) ----------------
__global__ __launch_bounds__(64) void proc_kernel(
    const int* __restrict__ colp, const float* __restrict__ pos,
    const float* __restrict__ pred, float* __restrict__ Rout,
    float* __restrict__ tout, float* __restrict__ qnorm) {
  int i = blockIdx.x * blockDim.x + threadIdx.x;
  if (i >= NS) return;
  int4 cia[8];
#pragma unroll
  for (int t = 0; t < 8; ++t)
    cia[t] = reinterpret_cast<const int4*>(colp + (size_t)i * DEG)[t];
  const int* cidx = reinterpret_cast<const int*>(cia);

  double sp[3] = {0, 0, 0}, sq[3] = {0, 0, 0};
  double spq[3][3] = {{0, 0, 0}, {0, 0, 0}, {0, 0, 0}};
#pragma unroll
  for (int e = 0; e < DEG; ++e) {
    int c = cidx[e];
    double p0 = pos[c * 3], p1 = pos[c * 3 + 1], p2 = pos[c * 3 + 2];
    double q0 = pred[c * 3], q1 = pred[c * 3 + 1], q2 = pred[c * 3 + 2];
    sp[0] += p0; sp[1] += p1; sp[2] += p2;
    sq[0] += q0; sq[1] += q1; sq[2] += q2;
    spq[0][0] += p0 * q0; spq[0][1] += p0 * q1; spq[0][2] += p0 * q2;
    spq[1][0] += p1 * q0; spq[1][1] += p1 * q1; spq[1][2] += p1 * q2;
    spq[2][0] += p2 * q0; spq[2][1] += p2 * q1; spq[2][2] += p2 * q2;
  }
  const double inv = 1.0 / 32.0;
  double A[3][3], sc[3], tcn[3];
  for (int a = 0; a < 3; ++a) {
    sc[a] = sp[a] * inv;
    tcn[a] = sq[a] * inv;
  }
  for (int a = 0; a < 3; ++a)
    for (int b = 0; b < 3; ++b) A[a][b] = spq[a][b] - sp[a] * sq[b] * inv;

  double S[3][3];
  for (int a = 0; a < 3; ++a)
    for (int b = 0; b < 3; ++b)
      S[a][b] = A[0][a] * A[0][b] + A[1][a] * A[1][b] + A[2][a] * A[2][b];
  double V[3][3] = {{1, 0, 0}, {0, 1, 0}, {0, 0, 1}};
  const int JP[3] = {0, 0, 1}, JQ[3] = {1, 2, 2};
  for (int sweep = 0; sweep < 6; ++sweep) {
    for (int r = 0; r < 3; ++r) {
      int p = JP[r], q = JQ[r];
      double apq = S[p][q];
      if (fabs(apq) < 1e-300) continue;
      double theta = (S[q][q] - S[p][p]) / (2.0 * apq);
      double t = copysign(1.0 / (fabs(theta) + sqrt(theta * theta + 1.0)), theta);
      double c = 1.0 / sqrt(t * t + 1.0);
      double s = t * c;
      double spp = S[p][p], sqq = S[q][q];
      S[p][p] = spp - t * apq;
      S[q][q] = sqq + t * apq;
      S[p][q] = 0.0; S[q][p] = 0.0;
      int k = 3 - p - q;
      double skp = S[k][p], skq = S[k][q];
      S[k][p] = S[p][k] = c * skp - s * skq;
      S[k][q] = S[q][k] = s * skp + c * skq;
      for (int mth = 0; mth < 3; ++mth) {
        double vp = V[mth][p], vq = V[mth][q];
        V[mth][p] = c * vp - s * vq;
        V[mth][q] = s * vp + c * vq;
      }
    }
  }
  double lam[3] = {S[0][0], S[1][1], S[2][2]};
  int i0 = 0, i1 = 1, i2 = 2, tmp;
  if (lam[i0] < lam[i1]) { tmp = i0; i0 = i1; i1 = tmp; }
  if (lam[i0] < lam[i2]) { tmp = i0; i0 = i2; i2 = tmp; }
  if (lam[i1] < lam[i2]) { tmp = i1; i1 = i2; i2 = tmp; }
  double v0[3] = {V[0][i0], V[1][i0], V[2][i0]};
  double v1[3] = {V[0][i1], V[1][i1], V[2][i1]};
  double v2[3] = {V[0][i2], V[1][i2], V[2][i2]};

  double Av0[3], Av1[3], Av2[3];
  for (int a = 0; a < 3; ++a) {
    Av0[a] = A[a][0] * v0[0] + A[a][1] * v0[1] + A[a][2] * v0[2];
    Av1[a] = A[a][0] * v1[0] + A[a][1] * v1[1] + A[a][2] * v1[2];
    Av2[a] = A[a][0] * v2[0] + A[a][1] * v2[1] + A[a][2] * v2[2];
  }
  double n0 = fmax(sqrt(Av0[0]*Av0[0] + Av0[1]*Av0[1] + Av0[2]*Av0[2]), 1e-300);
  double u0[3] = {Av0[0] / n0, Av0[1] / n0, Av0[2] / n0};
  double proj = u0[0]*Av1[0] + u0[1]*Av1[1] + u0[2]*Av1[2];
  double u1[3] = {Av1[0] - proj * u0[0], Av1[1] - proj * u0[1], Av1[2] - proj * u0[2]};
  double n1 = fmax(sqrt(u1[0]*u1[0] + u1[1]*u1[1] + u1[2]*u1[2]), 1e-300);
  u1[0] /= n1; u1[1] /= n1; u1[2] /= n1;
  double w[3] = {u0[1]*u1[2] - u0[2]*u1[1],
                 u0[2]*u1[0] - u0[0]*u1[2],
                 u0[0]*u1[1] - u0[1]*u1[0]};
  double dotw = Av2[0]*w[0] + Av2[1]*w[1] + Av2[2]*w[2];
  double sgn = (dotw < 0.0) ? -1.0 : 1.0;
  double detA = A[0][0]*(A[1][1]*A[2][2] - A[1][2]*A[2][1])
              - A[0][1]*(A[1][0]*A[2][2] - A[1][2]*A[2][0])
              + A[0][2]*(A[1][0]*A[2][1] - A[1][1]*A[2][0]);
  double d3 = ((detA < 0.0) ? -1.0 : 1.0) * sgn;

  double R[3][3];
  for (int a = 0; a < 3; ++a)
    for (int b = 0; b < 3; ++b)
      R[a][b] = u0[a]*v0[b] + u1[a]*v1[b] + d3 * w[a]*v2[b];

  for (int a = 0; a < 3; ++a)
    for (int b = 0; b < 3; ++b) Rout[i * 9 + a * 3 + b] = (float)R[a][b];
  double tr_[3];
  for (int a = 0; a < 3; ++a) {
    tr_[a] = tcn[a] - (R[a][0]*sc[0] + R[a][1]*sc[1] + R[a][2]*sc[2]);
    tout[i * 3 + a] = (float)tr_[a];
  }
  double pxi = pos[i * 3], pyi = pos[i * 3 + 1], pzi = pos[i * 3 + 2];
  double r0 = R[0][0]*pxi + R[0][1]*pyi + R[0][2]*pzi + tr_[0] - pred[i * 3];
  double r1 = R[1][0]*pxi + R[1][1]*pyi + R[1][2]*pzi + tr_[1] - pred[i * 3 + 1];
  double r2 = R[2][0]*pxi + R[2][1]*pyi + R[2][2]*pzi + tr_[2] - pred[i * 3 + 2];
  qnorm[i] = (float)(r0 * r0 + r1 * r1 + r2 * r2);
}

// ---------------- K3: per-node residual mean over neighbors ----------------
__global__ __launch_bounds__(64) void dst_kernel(
    const int* __restrict__ colp, const float* __restrict__ qn,
    float* __restrict__ dout) {
  int i = blockIdx.x * blockDim.x + threadIdx.x;
  if (i >= NS) return;
  int4 cia[8];
#pragma unroll
  for (int t = 0; t < 8; ++t)
    cia[t] = reinterpret_cast<const int4*>(colp + (size_t)i * DEG)[t];
  const int* cidx = reinterpret_cast<const int*>(cia);
  float s = 0.f;
#pragma unroll
  for (int e = 0; e < DEG; ++e) s += qn[cidx[e]];
  dout[i] = s * (1.0f / 32.0f);
}

extern "C" void kernel_launch(void* const* d_in, const int* in_sizes, int n_in,
                              void* d_out, int out_size, void* d_ws, size_t ws_size,
                              hipStream_t stream) {
  const float* sf  = (const float*)d_in[0];   // [N,128]
  const float* tf  = (const float*)d_in[1];   // [T,128]
  const float* tp  = (const float*)d_in[2];   // [T,3]
  const float* pos = (const float*)d_in[3];   // [N,3]
  const int*   ei  = (const int*)d_in[4];     // [2,E]
  float* out = (float*)d_out;                 // [N*9 | N*3 | N]
  char* ws = (char*)d_ws;
  // ws layout (~5.9 MB; qn aliases tfbx which is dead after topk):
  float*          tn    = (float*)(ws);                    // 27,648 B
  float*          tn256 = (float*)(ws + 28672);            // 27,648 B
  float*          pred  = (float*)(ws + 57344);            // 240,000 B
  uint*           pkall = (uint*)(ws + 297344);            // 20000*48*4 = 3,840,000 B
  unsigned short* tfbx  = (unsigned short*)(ws + 4137344); // 1,769,472 B
  float*          qn    = (float*)(ws + 4137344);          // alias (post-topk)
  const int* colp = ei + EDG;

  tn_cast_kernel<<<(TPAD * 64) / 256, 256, 0, stream>>>(tf, tn, tn256, tfbx);
  topk_kernel<<<(NS / RPB) * NCB, 256, 0, stream>>>(sf, tfbx, tn256, pkall);
  merge_kernel<<<NS / 4, 256, 0, stream>>>(sf, tf, tn, pkall, tp, pred);
  proc_kernel<<<(NS + 63) / 64, 64, 0, stream>>>(colp, pos, pred, out,
                                                 out + NS * 9, qn);
  dst_kernel<<<(NS + 63) / 64, 64, 0, stream>>>(colp, qn, out + NS * 12);
}